// Round 7
// baseline (528.096 us; speedup 1.0000x reference)
//
#include <hip/hip_runtime.h>
#include <hip/hip_bf16.h>

#define N_NODES 20000
#define MPAD    20096
#define E_EDGES 400000
#define LATENT 128
#define H1 256
#define HIDDEN 512
#define OUT_D 64
#define HEADS 4
#define NEG_SLOPE 0.2f
// fixed-pitch adjacency: deg ~ Binomial(400k, 1/20k) -> mean 20, sigma 4.47; 80 slots = 13+ sigma.
#define MAX_IN 80

typedef __attribute__((ext_vector_type(8))) __bf16 bf16x8;
typedef __attribute__((ext_vector_type(4))) float f32x4;
typedef __attribute__((ext_vector_type(4))) unsigned short u16x4;
typedef __attribute__((ext_vector_type(8))) unsigned short u16x8;

__device__ __forceinline__ unsigned short f2bf(float f) {
    union { float f; unsigned int u; } v; v.f = f;
    unsigned int r = v.u + 0x7fffu + ((v.u >> 16) & 1u);  // RNE
    return (unsigned short)(r >> 16);
}
__device__ __forceinline__ float bf2f(unsigned short u) {
    union { unsigned int u; float f; } v; v.u = ((unsigned int)u) << 16;
    return v.f;
}

// ---------------- D1: LDS-tiled transpose-convert + zero cur + zero barrier ----------------------
#define W1_TILES 32
#define W2_TILES 128
#define WG_TILES 128
#define CUR_BLKS ((N_NODES + 255) / 256)   // 79
#define PREP_BLKS (W1_TILES + W2_TILES + WG_TILES + CUR_BLKS)
__global__ __launch_bounds__(256)
void prep_kernel(const float* __restrict__ W1, const float* __restrict__ W2,
                 const float* __restrict__ Wg,
                 unsigned short* __restrict__ W1t, unsigned short* __restrict__ W2t,
                 unsigned short* __restrict__ Wgt, int* __restrict__ cur,
                 int* __restrict__ bar) {
    int b = blockIdx.x;
    if (b >= W1_TILES + W2_TILES + WG_TILES) {
        int t = (b - (W1_TILES + W2_TILES + WG_TILES)) * 256 + threadIdx.x;
        if (t < N_NODES) cur[t] = 0;
        if (t == N_NODES) *bar = 0;        // barrier counter zeroed every replay
        return;
    }
    const float* src; unsigned short* dst; int K, N, k0, n0;
    if (b < W1_TILES) {
        src = W1; dst = W1t; K = LATENT; N = H1;
        k0 = (b >> 3) * 32; n0 = (b & 7) * 32;
    } else if (b < W1_TILES + W2_TILES) {
        int t2 = b - W1_TILES;
        src = W2; dst = W2t; K = H1; N = HIDDEN;
        k0 = (t2 >> 4) * 32; n0 = (t2 & 15) * 32;
    } else {
        int t3 = b - W1_TILES - W2_TILES;
        src = Wg; dst = Wgt; K = HIDDEN; N = HEADS * OUT_D;
        k0 = (t3 >> 3) * 32; n0 = (t3 & 7) * 32;
    }
    __shared__ float tile[32][33];
    const int c = threadIdx.x & 31, r0 = threadIdx.x >> 5;
#pragma unroll
    for (int i = 0; i < 4; i++) {
        int r = r0 + i * 8;
        tile[r][c] = src[(size_t)(k0 + r) * N + n0 + c];       // coalesced read
    }
    __syncthreads();
#pragma unroll
    for (int i = 0; i < 4; i++) {
        int r = r0 + i * 8;
        dst[(size_t)(n0 + r) * K + k0 + c] = f2bf(tile[c][r]); // coalesced write
    }
}

// ---------------- D2: scatter prefix | MLP | manual grid barrier | gat ---------------------------
// R7: cooperative launch is rejected under graph capture (R6: kernel never ran). Same phase plan,
// regular launch + MANUAL barrier. Deadlock-free: 628 blocks x 50.2 KB LDS = 3 blocks/CU -> 768
// resident slots >= 628, no early returns, so every block is resident before any block spins.
// Cross-XCD visibility: __threadfence (agent-scope, L2 wb/inv) on both sides of the barrier.
#define TM 32
#define ZPITCH 136
#define XPITCH 264
#define X2PITCH 520
#define NBLOCKS (MPAD / TM)                 // 628

__global__ __launch_bounds__(256, 3)
void mega2(const float* __restrict__ z,
           const unsigned short* __restrict__ W1t,
           const unsigned short* __restrict__ W2t,
           const unsigned short* __restrict__ Wgt,
           const float* __restrict__ b1, const float* __restrict__ b2,
           const float* __restrict__ att_src, const float* __restrict__ att_dst,
           const float* __restrict__ bias_g, const int* __restrict__ ei,
           unsigned short* __restrict__ hb,
           float* __restrict__ a_src, float* __restrict__ a_dst,
           int* __restrict__ cur, int* __restrict__ adj,
           int* __restrict__ bar, float* __restrict__ out) {
    __shared__ unsigned short x2s[TM * X2PITCH];   // 33.3 KB; first 8.7 KB aliased as zbf
    __shared__ unsigned short x1s[TM * XPITCH];    // 16.9 KB (50.2 KB total)

    // ===== phase A: edge scatter prefix (all blocks, grid-strided, ~2.5 edges/thread) =====
    {
        int gid = blockIdx.x * 256 + threadIdx.x;
        for (int t = gid; t < E_EDGES; t += NBLOCKS * 256) {
            int s = ei[t], d = ei[E_EDGES + t];
            int idx = atomicAdd(&cur[d], 1);
            idx = min(idx, MAX_IN - 1);            // statistically unreachable clamp
            adj[d * MAX_IN + idx] = s;
        }
    }

    // ===== phase B: MLP (unchanged R15 body) =====
    {
        unsigned short* zbf = x2s;
        const int tid = threadIdx.x;
        const int wave = tid >> 6, lane = tid & 63;
        const int m0 = blockIdx.x * TM;
        const int fr = lane & 15, q = lane >> 4;

#define LDW1(kt, t)      (*(const bf16x8*)(W1t + (size_t)(nb1 + (t) * 16 + fr) * LATENT + (kt) * 32 + q * 8))
#define LDW2H(nh, kt, t) (*(const bf16x8*)(W2t + (size_t)(nb2 + (nh) * 64 + (t) * 16 + fr) * H1 + (kt) * 32 + q * 8))
#define LDW3(kt, t)      (*(const bf16x8*)(Wgt + (size_t)(nb3 + (t) * 16 + fr) * HIDDEN + (kt) * 32 + q * 8))

        const int nb1 = wave * 64;
        const int nb2 = wave * 128;
        const int head = wave;
        const int nb3 = wave * 64;

        bf16x8 w1a[4], w1b[4];
#pragma unroll
        for (int t = 0; t < 4; t++) w1a[t] = LDW1(0, t);

        {
            const int r = tid >> 3, c0 = (tid & 7) * 16;
            const int zrow = min(m0 + r, N_NODES - 1);
            const float* zp = z + (size_t)zrow * LATENT + c0;
#pragma unroll
            for (int i = 0; i < 4; i++) {
                f32x4 v = *(const f32x4*)(zp + i * 4);
                u16x4 p = { f2bf(v[0]), f2bf(v[1]), f2bf(v[2]), f2bf(v[3]) };
                *(u16x4*)(zbf + r * ZPITCH + c0 + i * 4) = p;
            }
        }
        __syncthreads();

        // ---- layer 1: K=128 (4 kt) ----
        f32x4 acc1[2][4] = {};
#pragma unroll
        for (int kt = 0; kt < 4; kt++) {
            bf16x8* wc = (kt & 1) ? w1b : w1a;
            bf16x8* wn = (kt & 1) ? w1a : w1b;
            if (kt < 3) {
#pragma unroll
                for (int t = 0; t < 4; t++) wn[t] = LDW1(kt + 1, t);
            }
            bf16x8 af[2];
#pragma unroll
            for (int t = 0; t < 2; t++)
                af[t] = *(const bf16x8*)(zbf + (t * 16 + fr) * ZPITCH + kt * 32 + q * 8);
#pragma unroll
            for (int mt = 0; mt < 2; mt++)
#pragma unroll
                for (int nt = 0; nt < 4; nt++)
                    acc1[mt][nt] = __builtin_amdgcn_mfma_f32_16x16x32_bf16(
                        wc[nt], af[mt], acc1[mt][nt], 0, 0, 0);
        }

        bf16x8 w2a[4], w2b[4];
#pragma unroll
        for (int t = 0; t < 4; t++) w2a[t] = LDW2H(0, 0, t);

        // layer-1 epilogue -> x1s
#pragma unroll
        for (int nt = 0; nt < 4; nt++) {
            const int n = nb1 + nt * 16 + q * 4;
            const f32x4 bv = *(const f32x4*)(b1 + n);
#pragma unroll
            for (int mt = 0; mt < 2; mt++) {
                u16x4 p;
#pragma unroll
                for (int r = 0; r < 4; r++) p[r] = f2bf(fmaxf(acc1[mt][nt][r] + bv[r], 0.f));
                *(u16x4*)(x1s + (mt * 16 + fr) * XPITCH + n) = p;
            }
        }
        __syncthreads();

        // ---- layer 2: K=256 (8 kt), two sequential 64-col halves ----
#pragma unroll
        for (int nh = 0; nh < 2; nh++) {
            if (nh == 1) {
#pragma unroll
                for (int t = 0; t < 4; t++) w2a[t] = LDW2H(1, 0, t);
            }
            f32x4 acc2[2][4] = {};
#pragma unroll
            for (int kt = 0; kt < 8; kt++) {
                bf16x8* wc = (kt & 1) ? w2b : w2a;
                bf16x8* wn = (kt & 1) ? w2a : w2b;
                if (kt < 7) {
#pragma unroll
                    for (int t = 0; t < 4; t++) wn[t] = LDW2H(nh, kt + 1, t);
                }
                bf16x8 af[2];
#pragma unroll
                for (int t = 0; t < 2; t++)
                    af[t] = *(const bf16x8*)(x1s + (t * 16 + fr) * XPITCH + kt * 32 + q * 8);
#pragma unroll
                for (int mt = 0; mt < 2; mt++)
#pragma unroll
                    for (int nt = 0; nt < 4; nt++)
                        acc2[mt][nt] = __builtin_amdgcn_mfma_f32_16x16x32_bf16(
                            wc[nt], af[mt], acc2[mt][nt], 0, 0, 0);
            }
#pragma unroll
            for (int nt = 0; nt < 4; nt++) {
                const int n = nb2 + nh * 64 + nt * 16 + q * 4;
                const f32x4 bv = *(const f32x4*)(b2 + n);
#pragma unroll
                for (int mt = 0; mt < 2; mt++) {
                    u16x4 p;
#pragma unroll
                    for (int r = 0; r < 4; r++) p[r] = f2bf(fmaxf(acc2[mt][nt][r] + bv[r], 0.f));
                    *(u16x4*)(x2s + (mt * 16 + fr) * X2PITCH + n) = p;
                }
            }
        }

        bf16x8 w3a[4], w3b[4];
#pragma unroll
        for (int t = 0; t < 4; t++) w3a[t] = LDW3(0, t);
        __syncthreads();

        // ---- layer 3: K=512 (16 kt) + att epilogue ----
        f32x4 acc3[2][4] = {};
#pragma unroll
        for (int kt = 0; kt < 16; kt++) {
            bf16x8* wc = (kt & 1) ? w3b : w3a;
            bf16x8* wn = (kt & 1) ? w3a : w3b;
            if (kt < 15) {
#pragma unroll
                for (int t = 0; t < 4; t++) wn[t] = LDW3(kt + 1, t);
            }
            bf16x8 af[2];
#pragma unroll
            for (int t = 0; t < 2; t++)
                af[t] = *(const bf16x8*)(x2s + (t * 16 + fr) * X2PITCH + kt * 32 + q * 8);
#pragma unroll
            for (int mt = 0; mt < 2; mt++)
#pragma unroll
                for (int nt = 0; nt < 4; nt++)
                    acc3[mt][nt] = __builtin_amdgcn_mfma_f32_16x16x32_bf16(
                        wc[nt], af[mt], acc3[mt][nt], 0, 0, 0);
        }

        {
            f32x4 asv[4], adv[4];
#pragma unroll
            for (int nt = 0; nt < 4; nt++) {
                asv[nt] = *(const f32x4*)(att_src + head * OUT_D + nt * 16 + q * 4);
                adv[nt] = *(const f32x4*)(att_dst + head * OUT_D + nt * 16 + q * 4);
            }
#pragma unroll
            for (int mt = 0; mt < 2; mt++) {
                const int row = m0 + mt * 16 + fr;
                float vs = 0.f, vd = 0.f;
#pragma unroll
                for (int nt = 0; nt < 4; nt++) {
                    u16x4 p;
#pragma unroll
                    for (int r = 0; r < 4; r++) {
                        float x = acc3[mt][nt][r];
                        p[r] = f2bf(x);
                        vs += x * asv[nt][r];
                        vd += x * adv[nt][r];
                    }
                    *(u16x4*)(hb + (size_t)row * (HEADS * OUT_D) + head * OUT_D + nt * 16 + q * 4) = p;
                }
                vs += __shfl_xor(vs, 16, 64); vs += __shfl_xor(vs, 32, 64);
                vd += __shfl_xor(vd, 16, 64); vd += __shfl_xor(vd, 32, 64);
                if (q == 0 && row < N_NODES) {
                    a_src[row * HEADS + head] = vs;
                    a_dst[row * HEADS + head] = vd;
                }
            }
        }
#undef LDW1
#undef LDW2H
#undef LDW3
    }

    // ===== manual grid barrier (release: threadfence; arrive+spin; acquire: threadfence) =====
    __threadfence();                 // each thread flushes its own stores device-wide (L2 wb)
    __syncthreads();                 // whole block done writing
    if (threadIdx.x == 0) {
        __hip_atomic_fetch_add(bar, 1, __ATOMIC_ACQ_REL, __HIP_MEMORY_SCOPE_AGENT);
        while (__hip_atomic_load(bar, __ATOMIC_ACQUIRE, __HIP_MEMORY_SCOPE_AGENT) < NBLOCKS)
            __builtin_amdgcn_s_sleep(2);
    }
    __syncthreads();
    __threadfence();                 // invalidate stale lines before cross-XCD reads

    // ===== phase C: gat (R5 shfl-adj), block-strided: 628 blocks x 8 nodes x 4 sweeps =====
    {
        const int wv = threadIdx.x >> 6, ln = threadIdx.x & 63;
        const int grp = ln >> 5, sl = ln & 31;
        const int h = sl >> 3, j = sl & 7;
        const int gbase = grp * 32;

        for (int d0 = blockIdx.x * 8; d0 < N_NODES; d0 += NBLOCKS * 8) {
            const int d = d0 + wv * 2 + grp;          // d0+7 <= 19999
            const int cnt = min(cur[d], MAX_IN);
            const int* arow = adj + d * MAX_IN;

            int myadj = (sl < cnt) ? arow[sl] : 0;    // one coalesced load covers cnt<=32 (99.7%)

            const float ad = a_dst[d * HEADS + h];
            const unsigned short* hp = hb + h * OUT_D + j * 8;

            float vself = a_src[d * HEADS + h] + ad;
            vself = (vself > 0.f) ? vself : NEG_SLOPE * vself;
            float sm = __expf(fminf(vself, 60.f));
            u16x8 gs = *(const u16x8*)(hp + (size_t)d * (HEADS * OUT_D));
            float acc[8];
#pragma unroll
            for (int r = 0; r < 8; r++) acc[r] = sm * bf2f(gs[r]);

            const int lim = cnt < 32 ? cnt : 32;
            int e = 0;
            for (; e + 7 < lim; e += 8) {
                int sx[8]; float fx[8]; u16x8 gx[8];
#pragma unroll
                for (int u = 0; u < 8; u++) sx[u] = __shfl(myadj, gbase + e + u, 64);
#pragma unroll
                for (int u = 0; u < 8; u++) fx[u] = a_src[sx[u] * HEADS + h];
#pragma unroll
                for (int u = 0; u < 8; u++) gx[u] = *(const u16x8*)(hp + (size_t)sx[u] * (HEADS * OUT_D));
#pragma unroll
                for (int u = 0; u < 8; u++) {
                    float v = fx[u] + ad;
                    v = (v > 0.f) ? v : NEG_SLOPE * v;
                    float w = __expf(fminf(v, 60.f));
                    sm += w;
#pragma unroll
                    for (int r = 0; r < 8; r++) acc[r] += w * bf2f(gx[u][r]);
                }
            }
            for (; e + 3 < lim; e += 4) {
                int sx[4]; float fx[4]; u16x8 gx[4];
#pragma unroll
                for (int u = 0; u < 4; u++) sx[u] = __shfl(myadj, gbase + e + u, 64);
#pragma unroll
                for (int u = 0; u < 4; u++) fx[u] = a_src[sx[u] * HEADS + h];
#pragma unroll
                for (int u = 0; u < 4; u++) gx[u] = *(const u16x8*)(hp + (size_t)sx[u] * (HEADS * OUT_D));
#pragma unroll
                for (int u = 0; u < 4; u++) {
                    float v = fx[u] + ad;
                    v = (v > 0.f) ? v : NEG_SLOPE * v;
                    float w = __expf(fminf(v, 60.f));
                    sm += w;
#pragma unroll
                    for (int r = 0; r < 8; r++) acc[r] += w * bf2f(gx[u][r]);
                }
            }
            for (; e < lim; e++) {
                int s = __shfl(myadj, gbase + e, 64);
                float v = a_src[s * HEADS + h] + ad;
                v = (v > 0.f) ? v : NEG_SLOPE * v;
                float w = __expf(fminf(v, 60.f));
                u16x8 g = *(const u16x8*)(hp + (size_t)s * (HEADS * OUT_D));
                sm += w;
#pragma unroll
                for (int r = 0; r < 8; r++) acc[r] += w * bf2f(g[r]);
            }
            for (int e2 = 32; e2 < cnt; e2++) {   // rare (deg >= 32, ~0.3% of nodes)
                int s = arow[e2];
                float v = a_src[s * HEADS + h] + ad;
                v = (v > 0.f) ? v : NEG_SLOPE * v;
                float w = __expf(fminf(v, 60.f));
                u16x8 g = *(const u16x8*)(hp + (size_t)s * (HEADS * OUT_D));
                sm += w;
#pragma unroll
                for (int r = 0; r < 8; r++) acc[r] += w * bf2f(g[r]);
            }

            const float inv = 1.f / (sm + 1e-16f);
#pragma unroll
            for (int r = 0; r < 8; r++) {
                acc[r] *= inv;
                acc[r] += __shfl_xor(acc[r], 8, 64);
                acc[r] += __shfl_xor(acc[r], 16, 64);
            }
            if (h == 0) {
                const f32x4 bg0 = *(const f32x4*)(bias_g + j * 8);
                const f32x4 bg1 = *(const f32x4*)(bias_g + j * 8 + 4);
                f32x4 o0 = { 0.25f * acc[0] + bg0[0], 0.25f * acc[1] + bg0[1],
                             0.25f * acc[2] + bg0[2], 0.25f * acc[3] + bg0[3] };
                f32x4 o1 = { 0.25f * acc[4] + bg1[0], 0.25f * acc[5] + bg1[1],
                             0.25f * acc[6] + bg1[2], 0.25f * acc[7] + bg1[3] };
                *(f32x4*)(out + (size_t)d * OUT_D + j * 8) = o0;
                *(f32x4*)(out + (size_t)d * OUT_D + j * 8 + 4) = o1;
            }
        }
    }
}

extern "C" void kernel_launch(void* const* d_in, const int* in_sizes, int n_in,
                              void* d_out, int out_size, void* d_ws, size_t ws_size,
                              hipStream_t stream) {
    const float* z       = (const float*)d_in[0];
    const float* W1      = (const float*)d_in[1];
    const float* b1      = (const float*)d_in[2];
    const float* W2      = (const float*)d_in[3];
    const float* b2      = (const float*)d_in[4];
    const float* Wg      = (const float*)d_in[5];
    const float* att_src = (const float*)d_in[6];
    const float* att_dst = (const float*)d_in[7];
    const float* bias_g  = (const float*)d_in[8];
    const int*   ei      = (const int*)d_in[9];
    float* out = (float*)d_out;

    char* ws = (char*)d_ws;
    size_t off = 0;
    auto carve = [&](size_t bytes) { void* p = ws + off; off += (bytes + 255) & ~(size_t)255; return p; };

    unsigned short* W1t = (unsigned short*)carve((size_t)H1 * LATENT * 2);
    unsigned short* W2t = (unsigned short*)carve((size_t)HIDDEN * H1 * 2);
    unsigned short* Wgt = (unsigned short*)carve((size_t)(HEADS * OUT_D) * HIDDEN * 2);
    unsigned short* hb  = (unsigned short*)carve((size_t)MPAD * HEADS * OUT_D * 2);
    float* a_src = (float*)carve((size_t)N_NODES * HEADS * 4);
    float* a_dst = (float*)carve((size_t)N_NODES * HEADS * 4);
    int*   cur   = (int*)carve((size_t)N_NODES * 4);
    int*   adj   = (int*)carve((size_t)MAX_IN * N_NODES * 4);
    int*   bar   = (int*)carve(256);

    // 2 dispatches: prep (transpose + zero cur/bar) -> mega2 (scatter | MLP | barrier | gat).
    prep_kernel<<<PREP_BLKS, 256, 0, stream>>>(W1, W2, Wg, W1t, W2t, Wgt, cur, bar);

    mega2<<<NBLOCKS, 256, 0, stream>>>(
        z, W1t, W2t, Wgt, b1, b2, att_src, att_dst, bias_g, ei,
        hb, a_src, a_dst, cur, adj, bar, out);
}

// Round 8
// 161.958 us; speedup vs baseline: 3.2607x; 3.2607x over previous
//
#include <hip/hip_runtime.h>
#include <hip/hip_bf16.h>

#define N_NODES 20000
#define MPAD    20096
#define E_EDGES 400000
#define LATENT 128
#define H1 256
#define HIDDEN 512
#define OUT_D 64
#define HEADS 4
#define NEG_SLOPE 0.2f
// fixed-pitch adjacency: deg ~ Binomial(400k, 1/20k) -> mean 20, sigma 4.47; 80 slots = 13+ sigma.
#define MAX_IN 80

// SESSION LESSONS (do not re-try):
//  R2: global f32 atomicAdd accumulation -> 100 us memory-side serialization. Recompute instead.
//  R6: hipLaunchCooperativeKernel is silently rejected under the harness's graph capture.
//  R7: manual grid barrier (agent-scope acquire spin + threadfence) -> per-XCD L2 invalidation
//      storm: FETCH 9->84 MB (hb refetched per XCD), 62->485 us. Dispatch boundaries are CHEAPER
//      than in-kernel grid sync on gfx950. 3-dispatch structure is the floor.

typedef __attribute__((ext_vector_type(8))) __bf16 bf16x8;
typedef __attribute__((ext_vector_type(4))) float f32x4;
typedef __attribute__((ext_vector_type(4))) unsigned short u16x4;
typedef __attribute__((ext_vector_type(8))) unsigned short u16x8;

__device__ __forceinline__ unsigned short f2bf(float f) {
    union { float f; unsigned int u; } v; v.f = f;
    unsigned int r = v.u + 0x7fffu + ((v.u >> 16) & 1u);  // RNE
    return (unsigned short)(r >> 16);
}
__device__ __forceinline__ float bf2f(unsigned short u) {
    union { unsigned int u; float f; } v; v.u = ((unsigned int)u) << 16;
    return v.f;
}

// ---------------- prep: LDS-tiled coalesced transpose-convert + cur zeroing -----------------------
#define W1_TILES 32
#define W2_TILES 128
#define WG_TILES 128
#define CUR_BLKS ((N_NODES + 255) / 256)   // 79
#define PREP_BLKS (W1_TILES + W2_TILES + WG_TILES + CUR_BLKS)
__global__ __launch_bounds__(256)
void prep_kernel(const float* __restrict__ W1, const float* __restrict__ W2,
                 const float* __restrict__ Wg,
                 unsigned short* __restrict__ W1t, unsigned short* __restrict__ W2t,
                 unsigned short* __restrict__ Wgt, int* __restrict__ cur) {
    int b = blockIdx.x;
    if (b >= W1_TILES + W2_TILES + WG_TILES) {
        int t = (b - (W1_TILES + W2_TILES + WG_TILES)) * 256 + threadIdx.x;
        if (t < N_NODES) cur[t] = 0;
        return;
    }
    const float* src; unsigned short* dst; int K, N, k0, n0;
    if (b < W1_TILES) {
        src = W1; dst = W1t; K = LATENT; N = H1;
        k0 = (b >> 3) * 32; n0 = (b & 7) * 32;
    } else if (b < W1_TILES + W2_TILES) {
        int t2 = b - W1_TILES;
        src = W2; dst = W2t; K = H1; N = HIDDEN;
        k0 = (t2 >> 4) * 32; n0 = (t2 & 15) * 32;
    } else {
        int t3 = b - W1_TILES - W2_TILES;
        src = Wg; dst = Wgt; K = HIDDEN; N = HEADS * OUT_D;
        k0 = (t3 >> 3) * 32; n0 = (t3 & 7) * 32;
    }
    __shared__ float tile[32][33];
    const int c = threadIdx.x & 31, r0 = threadIdx.x >> 5;
#pragma unroll
    for (int i = 0; i < 4; i++) {
        int r = r0 + i * 8;
        tile[r][c] = src[(size_t)(k0 + r) * N + n0 + c];       // coalesced read (c = n fast)
    }
    __syncthreads();
#pragma unroll
    for (int i = 0; i < 4; i++) {
        int r = r0 + i * 8;
        dst[(size_t)(n0 + r) * K + k0 + c] = f2bf(tile[c][r]); // coalesced write (c = k fast)
    }
}

// ---------------- merged: MLP (blocks 0..627, unchanged R15 config) || edge scatter ---------------
// R3-proven: scatter blocks (touch ONLY ei/cur/adj) drain under the co-resident MLP's latency
// shadow (+3.5 us vs pure MLP).
#define TM 32
#define ZPITCH 136
#define XPITCH 264
#define X2PITCH 520
#define MLP_BLOCKS (MPAD / TM)                  // 628
#define SCAT_BLOCKS ((E_EDGES + 255) / 256)     // 1563
__global__ __launch_bounds__(256, 4)
void mlp_scatter_kernel(const float* __restrict__ z,
                        const unsigned short* __restrict__ W1t,
                        const unsigned short* __restrict__ W2t,
                        const unsigned short* __restrict__ Wgt,
                        const float* __restrict__ b1, const float* __restrict__ b2,
                        const float* __restrict__ att_src, const float* __restrict__ att_dst,
                        const int* __restrict__ ei, int* __restrict__ cur,
                        int* __restrict__ adj,
                        unsigned short* __restrict__ hb,
                        float* __restrict__ a_src, float* __restrict__ a_dst) {
    __shared__ unsigned short x2s[TM * X2PITCH];   // 33.3 KB; first 8.7 KB aliased as zbf
    __shared__ unsigned short x1s[TM * XPITCH];    // 16.9 KB (50.2 KB total)

    if (blockIdx.x >= MLP_BLOCKS) {
        int t = (blockIdx.x - MLP_BLOCKS) * 256 + threadIdx.x;
        if (t < E_EDGES) {
            int s = ei[t], d = ei[E_EDGES + t];
            int idx = atomicAdd(&cur[d], 1);
            idx = min(idx, MAX_IN - 1);            // statistically unreachable clamp
            adj[d * MAX_IN + idx] = s;
        }
        return;
    }

    unsigned short* zbf = x2s;
    const int tid = threadIdx.x;
    const int wave = tid >> 6, lane = tid & 63;
    const int m0 = blockIdx.x * TM;
    const int fr = lane & 15, q = lane >> 4;

#define LDW1(kt, t)      (*(const bf16x8*)(W1t + (size_t)(nb1 + (t) * 16 + fr) * LATENT + (kt) * 32 + q * 8))
#define LDW2H(nh, kt, t) (*(const bf16x8*)(W2t + (size_t)(nb2 + (nh) * 64 + (t) * 16 + fr) * H1 + (kt) * 32 + q * 8))
#define LDW3(kt, t)      (*(const bf16x8*)(Wgt + (size_t)(nb3 + (t) * 16 + fr) * HIDDEN + (kt) * 32 + q * 8))

    const int nb1 = wave * 64;
    const int nb2 = wave * 128;
    const int head = wave;
    const int nb3 = wave * 64;

    bf16x8 w1a[4], w1b[4];
#pragma unroll
    for (int t = 0; t < 4; t++) w1a[t] = LDW1(0, t);

    {
        const int r = tid >> 3, c0 = (tid & 7) * 16;
        const int zrow = min(m0 + r, N_NODES - 1);
        const float* zp = z + (size_t)zrow * LATENT + c0;
#pragma unroll
        for (int i = 0; i < 4; i++) {
            f32x4 v = *(const f32x4*)(zp + i * 4);
            u16x4 p = { f2bf(v[0]), f2bf(v[1]), f2bf(v[2]), f2bf(v[3]) };
            *(u16x4*)(zbf + r * ZPITCH + c0 + i * 4) = p;
        }
    }
    __syncthreads();

    // ---- layer 1: K=128 (4 kt) ----
    f32x4 acc1[2][4] = {};
#pragma unroll
    for (int kt = 0; kt < 4; kt++) {
        bf16x8* wc = (kt & 1) ? w1b : w1a;
        bf16x8* wn = (kt & 1) ? w1a : w1b;
        if (kt < 3) {
#pragma unroll
            for (int t = 0; t < 4; t++) wn[t] = LDW1(kt + 1, t);
        }
        bf16x8 af[2];
#pragma unroll
        for (int t = 0; t < 2; t++)
            af[t] = *(const bf16x8*)(zbf + (t * 16 + fr) * ZPITCH + kt * 32 + q * 8);
#pragma unroll
        for (int mt = 0; mt < 2; mt++)
#pragma unroll
            for (int nt = 0; nt < 4; nt++)
                acc1[mt][nt] = __builtin_amdgcn_mfma_f32_16x16x32_bf16(
                    wc[nt], af[mt], acc1[mt][nt], 0, 0, 0);
    }

    bf16x8 w2a[4], w2b[4];
#pragma unroll
    for (int t = 0; t < 4; t++) w2a[t] = LDW2H(0, 0, t);

    // layer-1 epilogue -> x1s
#pragma unroll
    for (int nt = 0; nt < 4; nt++) {
        const int n = nb1 + nt * 16 + q * 4;
        const f32x4 bv = *(const f32x4*)(b1 + n);
#pragma unroll
        for (int mt = 0; mt < 2; mt++) {
            u16x4 p;
#pragma unroll
            for (int r = 0; r < 4; r++) p[r] = f2bf(fmaxf(acc1[mt][nt][r] + bv[r], 0.f));
            *(u16x4*)(x1s + (mt * 16 + fr) * XPITCH + n) = p;
        }
    }
    __syncthreads();

    // ---- layer 2: K=256 (8 kt), two sequential 64-col halves ----
#pragma unroll
    for (int nh = 0; nh < 2; nh++) {
        if (nh == 1) {
#pragma unroll
            for (int t = 0; t < 4; t++) w2a[t] = LDW2H(1, 0, t);
        }
        f32x4 acc2[2][4] = {};
#pragma unroll
        for (int kt = 0; kt < 8; kt++) {
            bf16x8* wc = (kt & 1) ? w2b : w2a;
            bf16x8* wn = (kt & 1) ? w2a : w2b;
            if (kt < 7) {
#pragma unroll
                for (int t = 0; t < 4; t++) wn[t] = LDW2H(nh, kt + 1, t);
            }
            bf16x8 af[2];
#pragma unroll
            for (int t = 0; t < 2; t++)
                af[t] = *(const bf16x8*)(x1s + (t * 16 + fr) * XPITCH + kt * 32 + q * 8);
#pragma unroll
            for (int mt = 0; mt < 2; mt++)
#pragma unroll
                for (int nt = 0; nt < 4; nt++)
                    acc2[mt][nt] = __builtin_amdgcn_mfma_f32_16x16x32_bf16(
                        wc[nt], af[mt], acc2[mt][nt], 0, 0, 0);
        }
#pragma unroll
        for (int nt = 0; nt < 4; nt++) {
            const int n = nb2 + nh * 64 + nt * 16 + q * 4;
            const f32x4 bv = *(const f32x4*)(b2 + n);
#pragma unroll
            for (int mt = 0; mt < 2; mt++) {
                u16x4 p;
#pragma unroll
                for (int r = 0; r < 4; r++) p[r] = f2bf(fmaxf(acc2[mt][nt][r] + bv[r], 0.f));
                *(u16x4*)(x2s + (mt * 16 + fr) * X2PITCH + n) = p;
            }
        }
    }

    bf16x8 w3a[4], w3b[4];
#pragma unroll
    for (int t = 0; t < 4; t++) w3a[t] = LDW3(0, t);
    __syncthreads();

    // ---- layer 3: K=512 (16 kt) + att epilogue ----
    f32x4 acc3[2][4] = {};
#pragma unroll
    for (int kt = 0; kt < 16; kt++) {
        bf16x8* wc = (kt & 1) ? w3b : w3a;
        bf16x8* wn = (kt & 1) ? w3a : w3b;
        if (kt < 15) {
#pragma unroll
            for (int t = 0; t < 4; t++) wn[t] = LDW3(kt + 1, t);
        }
        bf16x8 af[2];
#pragma unroll
        for (int t = 0; t < 2; t++)
            af[t] = *(const bf16x8*)(x2s + (t * 16 + fr) * X2PITCH + kt * 32 + q * 8);
#pragma unroll
        for (int mt = 0; mt < 2; mt++)
#pragma unroll
            for (int nt = 0; nt < 4; nt++)
                acc3[mt][nt] = __builtin_amdgcn_mfma_f32_16x16x32_bf16(
                    wc[nt], af[mt], acc3[mt][nt], 0, 0, 0);
    }

    {
        f32x4 asv[4], adv[4];
#pragma unroll
        for (int nt = 0; nt < 4; nt++) {
            asv[nt] = *(const f32x4*)(att_src + head * OUT_D + nt * 16 + q * 4);
            adv[nt] = *(const f32x4*)(att_dst + head * OUT_D + nt * 16 + q * 4);
        }
#pragma unroll
        for (int mt = 0; mt < 2; mt++) {
            const int row = m0 + mt * 16 + fr;
            float vs = 0.f, vd = 0.f;
#pragma unroll
            for (int nt = 0; nt < 4; nt++) {
                u16x4 p;
#pragma unroll
                for (int r = 0; r < 4; r++) {
                    float x = acc3[mt][nt][r];
                    p[r] = f2bf(x);
                    vs += x * asv[nt][r];
                    vd += x * adv[nt][r];
                }
                *(u16x4*)(hb + (size_t)row * (HEADS * OUT_D) + head * OUT_D + nt * 16 + q * 4) = p;
            }
            vs += __shfl_xor(vs, 16, 64); vs += __shfl_xor(vs, 32, 64);
            vd += __shfl_xor(vd, 16, 64); vd += __shfl_xor(vd, 32, 64);
            if (q == 0 && row < N_NODES) {
                a_src[row * HEADS + head] = vs;
                a_dst[row * HEADS + head] = vd;
            }
        }
    }
#undef LDW1
#undef LDW2H
#undef LDW3
}

// ---------------- single-pass gather-aggregate, adj broadcast via shfl (R5-proven) ----------------
__global__ __launch_bounds__(256)
void fused_gat(const int* __restrict__ adj, const int* __restrict__ cur,
               const float* __restrict__ a_src, const float* __restrict__ a_dst,
               const unsigned short* __restrict__ hb,
               const float* __restrict__ bias_g, float* __restrict__ out) {
    const int wave = threadIdx.x >> 6, lane = threadIdx.x & 63;
    const int grp = lane >> 5, sl = lane & 31;
    const int d = blockIdx.x * 8 + wave * 2 + grp;   // 2500 blocks x 8 nodes
    const int h = sl >> 3, j = sl & 7;
    const int cnt = min(cur[d], MAX_IN);
    const int* arow = adj + d * MAX_IN;
    const int gbase = grp * 32;                      // shfl source-lane base for this group

    // one coalesced adjacency load: lane sl holds edge sl
    int myadj = (sl < cnt) ? arow[sl] : 0;

    const float ad = a_dst[d * HEADS + h];
    const unsigned short* hp = hb + h * OUT_D + j * 8;

    // self-loop seeds accumulators
    float vself = a_src[d * HEADS + h] + ad;
    vself = (vself > 0.f) ? vself : NEG_SLOPE * vself;
    float sm = __expf(fminf(vself, 60.f));
    u16x8 gs = *(const u16x8*)(hp + (size_t)d * (HEADS * OUT_D));
    float acc[8];
#pragma unroll
    for (int r = 0; r < 8; r++) acc[r] = sm * bf2f(gs[r]);

    const int lim = cnt < 32 ? cnt : 32;
    int e = 0;
    for (; e + 7 < lim; e += 8) {
        int sx[8]; float fx[8]; u16x8 gx[8];
#pragma unroll
        for (int u = 0; u < 8; u++) sx[u] = __shfl(myadj, gbase + e + u, 64);
#pragma unroll
        for (int u = 0; u < 8; u++) fx[u] = a_src[sx[u] * HEADS + h];
#pragma unroll
        for (int u = 0; u < 8; u++) gx[u] = *(const u16x8*)(hp + (size_t)sx[u] * (HEADS * OUT_D));
#pragma unroll
        for (int u = 0; u < 8; u++) {
            float v = fx[u] + ad;
            v = (v > 0.f) ? v : NEG_SLOPE * v;
            float w = __expf(fminf(v, 60.f));
            sm += w;
#pragma unroll
            for (int r = 0; r < 8; r++) acc[r] += w * bf2f(gx[u][r]);
        }
    }
    for (; e + 3 < lim; e += 4) {
        int sx[4]; float fx[4]; u16x8 gx[4];
#pragma unroll
        for (int u = 0; u < 4; u++) sx[u] = __shfl(myadj, gbase + e + u, 64);
#pragma unroll
        for (int u = 0; u < 4; u++) fx[u] = a_src[sx[u] * HEADS + h];
#pragma unroll
        for (int u = 0; u < 4; u++) gx[u] = *(const u16x8*)(hp + (size_t)sx[u] * (HEADS * OUT_D));
#pragma unroll
        for (int u = 0; u < 4; u++) {
            float v = fx[u] + ad;
            v = (v > 0.f) ? v : NEG_SLOPE * v;
            float w = __expf(fminf(v, 60.f));
            sm += w;
#pragma unroll
            for (int r = 0; r < 8; r++) acc[r] += w * bf2f(gx[u][r]);
        }
    }
    for (; e < lim; e++) {
        int s = __shfl(myadj, gbase + e, 64);
        float v = a_src[s * HEADS + h] + ad;
        v = (v > 0.f) ? v : NEG_SLOPE * v;
        float w = __expf(fminf(v, 60.f));
        u16x8 g = *(const u16x8*)(hp + (size_t)s * (HEADS * OUT_D));
        sm += w;
#pragma unroll
        for (int r = 0; r < 8; r++) acc[r] += w * bf2f(g[r]);
    }
    for (int e2 = 32; e2 < cnt; e2++) {   // rare (deg >= 32, ~0.3% of nodes)
        int s = arow[e2];
        float v = a_src[s * HEADS + h] + ad;
        v = (v > 0.f) ? v : NEG_SLOPE * v;
        float w = __expf(fminf(v, 60.f));
        u16x8 g = *(const u16x8*)(hp + (size_t)s * (HEADS * OUT_D));
        sm += w;
#pragma unroll
        for (int r = 0; r < 8; r++) acc[r] += w * bf2f(g[r]);
    }

    // per-head normalize, then mean over heads (shfl_xor 8/16 stays inside the 32-lane group)
    const float inv = 1.f / (sm + 1e-16f);
#pragma unroll
    for (int r = 0; r < 8; r++) {
        acc[r] *= inv;
        acc[r] += __shfl_xor(acc[r], 8, 64);
        acc[r] += __shfl_xor(acc[r], 16, 64);
    }
    if (h == 0) {
        const f32x4 bg0 = *(const f32x4*)(bias_g + j * 8);
        const f32x4 bg1 = *(const f32x4*)(bias_g + j * 8 + 4);
        f32x4 o0 = { 0.25f * acc[0] + bg0[0], 0.25f * acc[1] + bg0[1],
                     0.25f * acc[2] + bg0[2], 0.25f * acc[3] + bg0[3] };
        f32x4 o1 = { 0.25f * acc[4] + bg1[0], 0.25f * acc[5] + bg1[1],
                     0.25f * acc[6] + bg1[2], 0.25f * acc[7] + bg1[3] };
        *(f32x4*)(out + (size_t)d * OUT_D + j * 8) = o0;
        *(f32x4*)(out + (size_t)d * OUT_D + j * 8 + 4) = o1;
    }
}

extern "C" void kernel_launch(void* const* d_in, const int* in_sizes, int n_in,
                              void* d_out, int out_size, void* d_ws, size_t ws_size,
                              hipStream_t stream) {
    const float* z       = (const float*)d_in[0];
    const float* W1      = (const float*)d_in[1];
    const float* b1      = (const float*)d_in[2];
    const float* W2      = (const float*)d_in[3];
    const float* b2      = (const float*)d_in[4];
    const float* Wg      = (const float*)d_in[5];
    const float* att_src = (const float*)d_in[6];
    const float* att_dst = (const float*)d_in[7];
    const float* bias_g  = (const float*)d_in[8];
    const int*   ei      = (const int*)d_in[9];
    float* out = (float*)d_out;

    char* ws = (char*)d_ws;
    size_t off = 0;
    auto carve = [&](size_t bytes) { void* p = ws + off; off += (bytes + 255) & ~(size_t)255; return p; };

    unsigned short* W1t = (unsigned short*)carve((size_t)H1 * LATENT * 2);
    unsigned short* W2t = (unsigned short*)carve((size_t)HIDDEN * H1 * 2);
    unsigned short* Wgt = (unsigned short*)carve((size_t)(HEADS * OUT_D) * HIDDEN * 2);
    unsigned short* hb  = (unsigned short*)carve((size_t)MPAD * HEADS * OUT_D * 2);
    float* a_src = (float*)carve((size_t)N_NODES * HEADS * 4);
    float* a_dst = (float*)carve((size_t)N_NODES * HEADS * 4);
    int*   cur   = (int*)carve((size_t)N_NODES * 4);
    int*   adj   = (int*)carve((size_t)MAX_IN * N_NODES * 4);

    // 3 dispatches (proven floor structure, R5 = 161.8 us).
    prep_kernel<<<PREP_BLKS, 256, 0, stream>>>(W1, W2, Wg, W1t, W2t, Wgt, cur);

    mlp_scatter_kernel<<<MLP_BLOCKS + SCAT_BLOCKS, 256, 0, stream>>>(
        z, W1t, W2t, Wgt, b1, b2, att_src, att_dst, ei, cur, adj, hb, a_src, a_dst);

    fused_gat<<<N_NODES / 8, 256, 0, stream>>>(
        adj, cur, a_src, a_dst, hb, bias_g, out);
}

// Round 9
// 160.729 us; speedup vs baseline: 3.2856x; 1.0077x over previous
//
#include <hip/hip_runtime.h>
#include <hip/hip_bf16.h>

#define N_NODES 20000
#define MPAD    20096
#define E_EDGES 400000
#define LATENT 128
#define H1 256
#define HIDDEN 512
#define OUT_D 64
#define HEADS 4
#define NEG_SLOPE 0.2f
// fixed-pitch adjacency: deg ~ Binomial(400k, 1/20k) -> mean 20, sigma 4.47; 80 slots = 13+ sigma.
#define MAX_IN 80

// SESSION LESSONS (do not re-try):
//  R2: global f32 atomicAdd accumulation -> 100 us memory-side serialization. Recompute instead.
//  R6: hipLaunchCooperativeKernel is silently rejected under the harness's graph capture.
//  R7: manual grid barrier (agent-scope acquire spin + threadfence) -> per-XCD L2 invalidation
//      storm: FETCH 9->84 MB, 62->485 us. Dispatch boundaries are CHEAPER than in-kernel grid
//      sync on gfx950. 3-dispatch structure is the floor.
//  R9 (this round): scatter as 140 PERSISTENT blocks (= free co-residency slots: 768 - 628 MLP),
//      so all scatter work drains inside the MLP's latency shadow instead of 2 extra block-waves.

typedef __attribute__((ext_vector_type(8))) __bf16 bf16x8;
typedef __attribute__((ext_vector_type(4))) float f32x4;
typedef __attribute__((ext_vector_type(4))) unsigned short u16x4;
typedef __attribute__((ext_vector_type(8))) unsigned short u16x8;

__device__ __forceinline__ unsigned short f2bf(float f) {
    union { float f; unsigned int u; } v; v.f = f;
    unsigned int r = v.u + 0x7fffu + ((v.u >> 16) & 1u);  // RNE
    return (unsigned short)(r >> 16);
}
__device__ __forceinline__ float bf2f(unsigned short u) {
    union { unsigned int u; float f; } v; v.u = ((unsigned int)u) << 16;
    return v.f;
}

// ---------------- prep: LDS-tiled coalesced transpose-convert + cur zeroing -----------------------
#define W1_TILES 32
#define W2_TILES 128
#define WG_TILES 128
#define CUR_BLKS ((N_NODES + 255) / 256)   // 79
#define PREP_BLKS (W1_TILES + W2_TILES + WG_TILES + CUR_BLKS)
__global__ __launch_bounds__(256)
void prep_kernel(const float* __restrict__ W1, const float* __restrict__ W2,
                 const float* __restrict__ Wg,
                 unsigned short* __restrict__ W1t, unsigned short* __restrict__ W2t,
                 unsigned short* __restrict__ Wgt, int* __restrict__ cur) {
    int b = blockIdx.x;
    if (b >= W1_TILES + W2_TILES + WG_TILES) {
        int t = (b - (W1_TILES + W2_TILES + WG_TILES)) * 256 + threadIdx.x;
        if (t < N_NODES) cur[t] = 0;
        return;
    }
    const float* src; unsigned short* dst; int K, N, k0, n0;
    if (b < W1_TILES) {
        src = W1; dst = W1t; K = LATENT; N = H1;
        k0 = (b >> 3) * 32; n0 = (b & 7) * 32;
    } else if (b < W1_TILES + W2_TILES) {
        int t2 = b - W1_TILES;
        src = W2; dst = W2t; K = H1; N = HIDDEN;
        k0 = (t2 >> 4) * 32; n0 = (t2 & 15) * 32;
    } else {
        int t3 = b - W1_TILES - W2_TILES;
        src = Wg; dst = Wgt; K = HIDDEN; N = HEADS * OUT_D;
        k0 = (t3 >> 3) * 32; n0 = (t3 & 7) * 32;
    }
    __shared__ float tile[32][33];
    const int c = threadIdx.x & 31, r0 = threadIdx.x >> 5;
#pragma unroll
    for (int i = 0; i < 4; i++) {
        int r = r0 + i * 8;
        tile[r][c] = src[(size_t)(k0 + r) * N + n0 + c];       // coalesced read (c = n fast)
    }
    __syncthreads();
#pragma unroll
    for (int i = 0; i < 4; i++) {
        int r = r0 + i * 8;
        dst[(size_t)(n0 + r) * K + k0 + c] = f2bf(tile[c][r]); // coalesced write (c = k fast)
    }
}

// ---------------- merged: MLP (blocks 0..627, unchanged R15 config) || persistent scatter ---------
// R3-proven shadow-overlap; R9: scatter sized to the free slots so it drains fully under the MLP.
#define TM 32
#define ZPITCH 136
#define XPITCH 264
#define X2PITCH 520
#define MLP_BLOCKS (MPAD / TM)                  // 628
#define SCAT_BLOCKS 140                         // 768 co-residency slots - 628 MLP blocks
__global__ __launch_bounds__(256, 4)
void mlp_scatter_kernel(const float* __restrict__ z,
                        const unsigned short* __restrict__ W1t,
                        const unsigned short* __restrict__ W2t,
                        const unsigned short* __restrict__ Wgt,
                        const float* __restrict__ b1, const float* __restrict__ b2,
                        const float* __restrict__ att_src, const float* __restrict__ att_dst,
                        const int* __restrict__ ei, int* __restrict__ cur,
                        unsigned short* __restrict__ adj,
                        unsigned short* __restrict__ hb,
                        float* __restrict__ a_src, float* __restrict__ a_dst) {
    __shared__ unsigned short x2s[TM * X2PITCH];   // 33.3 KB; first 8.7 KB aliased as zbf
    __shared__ unsigned short x1s[TM * XPITCH];    // 16.9 KB (50.2 KB total)

    if (blockIdx.x >= MLP_BLOCKS) {
        // persistent scatter: 140 blocks grid-stride all 400k edges (~11 edges/thread, coalesced)
        int t0 = (blockIdx.x - MLP_BLOCKS) * 256 + threadIdx.x;
        for (int t = t0; t < E_EDGES; t += SCAT_BLOCKS * 256) {
            int s = ei[t], d = ei[E_EDGES + t];
            int idx = atomicAdd(&cur[d], 1);
            idx = min(idx, MAX_IN - 1);            // statistically unreachable clamp
            adj[d * MAX_IN + idx] = (unsigned short)s;   // node ids < 20000 < 65536
        }
        return;
    }

    unsigned short* zbf = x2s;
    const int tid = threadIdx.x;
    const int wave = tid >> 6, lane = tid & 63;
    const int m0 = blockIdx.x * TM;
    const int fr = lane & 15, q = lane >> 4;

#define LDW1(kt, t)      (*(const bf16x8*)(W1t + (size_t)(nb1 + (t) * 16 + fr) * LATENT + (kt) * 32 + q * 8))
#define LDW2H(nh, kt, t) (*(const bf16x8*)(W2t + (size_t)(nb2 + (nh) * 64 + (t) * 16 + fr) * H1 + (kt) * 32 + q * 8))
#define LDW3(kt, t)      (*(const bf16x8*)(Wgt + (size_t)(nb3 + (t) * 16 + fr) * HIDDEN + (kt) * 32 + q * 8))

    const int nb1 = wave * 64;
    const int nb2 = wave * 128;
    const int head = wave;
    const int nb3 = wave * 64;

    bf16x8 w1a[4], w1b[4];
#pragma unroll
    for (int t = 0; t < 4; t++) w1a[t] = LDW1(0, t);

    {
        const int r = tid >> 3, c0 = (tid & 7) * 16;
        const int zrow = min(m0 + r, N_NODES - 1);
        const float* zp = z + (size_t)zrow * LATENT + c0;
#pragma unroll
        for (int i = 0; i < 4; i++) {
            f32x4 v = *(const f32x4*)(zp + i * 4);
            u16x4 p = { f2bf(v[0]), f2bf(v[1]), f2bf(v[2]), f2bf(v[3]) };
            *(u16x4*)(zbf + r * ZPITCH + c0 + i * 4) = p;
        }
    }
    __syncthreads();

    // ---- layer 1: K=128 (4 kt) ----
    f32x4 acc1[2][4] = {};
#pragma unroll
    for (int kt = 0; kt < 4; kt++) {
        bf16x8* wc = (kt & 1) ? w1b : w1a;
        bf16x8* wn = (kt & 1) ? w1a : w1b;
        if (kt < 3) {
#pragma unroll
            for (int t = 0; t < 4; t++) wn[t] = LDW1(kt + 1, t);
        }
        bf16x8 af[2];
#pragma unroll
        for (int t = 0; t < 2; t++)
            af[t] = *(const bf16x8*)(zbf + (t * 16 + fr) * ZPITCH + kt * 32 + q * 8);
#pragma unroll
        for (int mt = 0; mt < 2; mt++)
#pragma unroll
            for (int nt = 0; nt < 4; nt++)
                acc1[mt][nt] = __builtin_amdgcn_mfma_f32_16x16x32_bf16(
                    wc[nt], af[mt], acc1[mt][nt], 0, 0, 0);
    }

    bf16x8 w2a[4], w2b[4];
#pragma unroll
    for (int t = 0; t < 4; t++) w2a[t] = LDW2H(0, 0, t);

    // layer-1 epilogue -> x1s
#pragma unroll
    for (int nt = 0; nt < 4; nt++) {
        const int n = nb1 + nt * 16 + q * 4;
        const f32x4 bv = *(const f32x4*)(b1 + n);
#pragma unroll
        for (int mt = 0; mt < 2; mt++) {
            u16x4 p;
#pragma unroll
            for (int r = 0; r < 4; r++) p[r] = f2bf(fmaxf(acc1[mt][nt][r] + bv[r], 0.f));
            *(u16x4*)(x1s + (mt * 16 + fr) * XPITCH + n) = p;
        }
    }
    __syncthreads();

    // ---- layer 2: K=256 (8 kt), two sequential 64-col halves ----
#pragma unroll
    for (int nh = 0; nh < 2; nh++) {
        if (nh == 1) {
#pragma unroll
            for (int t = 0; t < 4; t++) w2a[t] = LDW2H(1, 0, t);
        }
        f32x4 acc2[2][4] = {};
#pragma unroll
        for (int kt = 0; kt < 8; kt++) {
            bf16x8* wc = (kt & 1) ? w2b : w2a;
            bf16x8* wn = (kt & 1) ? w2a : w2b;
            if (kt < 7) {
#pragma unroll
                for (int t = 0; t < 4; t++) wn[t] = LDW2H(nh, kt + 1, t);
            }
            bf16x8 af[2];
#pragma unroll
            for (int t = 0; t < 2; t++)
                af[t] = *(const bf16x8*)(x1s + (t * 16 + fr) * XPITCH + kt * 32 + q * 8);
#pragma unroll
            for (int mt = 0; mt < 2; mt++)
#pragma unroll
                for (int nt = 0; nt < 4; nt++)
                    acc2[mt][nt] = __builtin_amdgcn_mfma_f32_16x16x32_bf16(
                        wc[nt], af[mt], acc2[mt][nt], 0, 0, 0);
        }
#pragma unroll
        for (int nt = 0; nt < 4; nt++) {
            const int n = nb2 + nh * 64 + nt * 16 + q * 4;
            const f32x4 bv = *(const f32x4*)(b2 + n);
#pragma unroll
            for (int mt = 0; mt < 2; mt++) {
                u16x4 p;
#pragma unroll
                for (int r = 0; r < 4; r++) p[r] = f2bf(fmaxf(acc2[mt][nt][r] + bv[r], 0.f));
                *(u16x4*)(x2s + (mt * 16 + fr) * X2PITCH + n) = p;
            }
        }
    }

    bf16x8 w3a[4], w3b[4];
#pragma unroll
    for (int t = 0; t < 4; t++) w3a[t] = LDW3(0, t);
    __syncthreads();

    // ---- layer 3: K=512 (16 kt) + att epilogue ----
    f32x4 acc3[2][4] = {};
#pragma unroll
    for (int kt = 0; kt < 16; kt++) {
        bf16x8* wc = (kt & 1) ? w3b : w3a;
        bf16x8* wn = (kt & 1) ? w3a : w3b;
        if (kt < 15) {
#pragma unroll
            for (int t = 0; t < 4; t++) wn[t] = LDW3(kt + 1, t);
        }
        bf16x8 af[2];
#pragma unroll
        for (int t = 0; t < 2; t++)
            af[t] = *(const bf16x8*)(x2s + (t * 16 + fr) * X2PITCH + kt * 32 + q * 8);
#pragma unroll
        for (int mt = 0; mt < 2; mt++)
#pragma unroll
            for (int nt = 0; nt < 4; nt++)
                acc3[mt][nt] = __builtin_amdgcn_mfma_f32_16x16x32_bf16(
                    wc[nt], af[mt], acc3[mt][nt], 0, 0, 0);
    }

    {
        f32x4 asv[4], adv[4];
#pragma unroll
        for (int nt = 0; nt < 4; nt++) {
            asv[nt] = *(const f32x4*)(att_src + head * OUT_D + nt * 16 + q * 4);
            adv[nt] = *(const f32x4*)(att_dst + head * OUT_D + nt * 16 + q * 4);
        }
#pragma unroll
        for (int mt = 0; mt < 2; mt++) {
            const int row = m0 + mt * 16 + fr;
            float vs = 0.f, vd = 0.f;
#pragma unroll
            for (int nt = 0; nt < 4; nt++) {
                u16x4 p;
#pragma unroll
                for (int r = 0; r < 4; r++) {
                    float x = acc3[mt][nt][r];
                    p[r] = f2bf(x);
                    vs += x * asv[nt][r];
                    vd += x * adv[nt][r];
                }
                *(u16x4*)(hb + (size_t)row * (HEADS * OUT_D) + head * OUT_D + nt * 16 + q * 4) = p;
            }
            vs += __shfl_xor(vs, 16, 64); vs += __shfl_xor(vs, 32, 64);
            vd += __shfl_xor(vd, 16, 64); vd += __shfl_xor(vd, 32, 64);
            if (q == 0 && row < N_NODES) {
                a_src[row * HEADS + head] = vs;
                a_dst[row * HEADS + head] = vd;
            }
        }
    }
#undef LDW1
#undef LDW2H
#undef LDW3
}

// ---------------- single-pass gather-aggregate, adj broadcast via shfl (R5-proven, u16 adj) -------
__global__ __launch_bounds__(256)
void fused_gat(const unsigned short* __restrict__ adj, const int* __restrict__ cur,
               const float* __restrict__ a_src, const float* __restrict__ a_dst,
               const unsigned short* __restrict__ hb,
               const float* __restrict__ bias_g, float* __restrict__ out) {
    const int wave = threadIdx.x >> 6, lane = threadIdx.x & 63;
    const int grp = lane >> 5, sl = lane & 31;
    const int d = blockIdx.x * 8 + wave * 2 + grp;   // 2500 blocks x 8 nodes
    const int h = sl >> 3, j = sl & 7;
    const int cnt = min(cur[d], MAX_IN);
    const unsigned short* arow = adj + d * MAX_IN;
    const int gbase = grp * 32;                      // shfl source-lane base for this group

    // one coalesced adjacency load: lane sl holds edge sl (64 B per 32-lane group)
    int myadj = (sl < cnt) ? (int)arow[sl] : 0;

    const float ad = a_dst[d * HEADS + h];
    const unsigned short* hp = hb + h * OUT_D + j * 8;

    // self-loop seeds accumulators
    float vself = a_src[d * HEADS + h] + ad;
    vself = (vself > 0.f) ? vself : NEG_SLOPE * vself;
    float sm = __expf(fminf(vself, 60.f));
    u16x8 gs = *(const u16x8*)(hp + (size_t)d * (HEADS * OUT_D));
    float acc[8];
#pragma unroll
    for (int r = 0; r < 8; r++) acc[r] = sm * bf2f(gs[r]);

    const int lim = cnt < 32 ? cnt : 32;
    int e = 0;
    for (; e + 7 < lim; e += 8) {
        int sx[8]; float fx[8]; u16x8 gx[8];
#pragma unroll
        for (int u = 0; u < 8; u++) sx[u] = __shfl(myadj, gbase + e + u, 64);
#pragma unroll
        for (int u = 0; u < 8; u++) fx[u] = a_src[sx[u] * HEADS + h];
#pragma unroll
        for (int u = 0; u < 8; u++) gx[u] = *(const u16x8*)(hp + (size_t)sx[u] * (HEADS * OUT_D));
#pragma unroll
        for (int u = 0; u < 8; u++) {
            float v = fx[u] + ad;
            v = (v > 0.f) ? v : NEG_SLOPE * v;
            float w = __expf(fminf(v, 60.f));
            sm += w;
#pragma unroll
            for (int r = 0; r < 8; r++) acc[r] += w * bf2f(gx[u][r]);
        }
    }
    for (; e + 3 < lim; e += 4) {
        int sx[4]; float fx[4]; u16x8 gx[4];
#pragma unroll
        for (int u = 0; u < 4; u++) sx[u] = __shfl(myadj, gbase + e + u, 64);
#pragma unroll
        for (int u = 0; u < 4; u++) fx[u] = a_src[sx[u] * HEADS + h];
#pragma unroll
        for (int u = 0; u < 4; u++) gx[u] = *(const u16x8*)(hp + (size_t)sx[u] * (HEADS * OUT_D));
#pragma unroll
        for (int u = 0; u < 4; u++) {
            float v = fx[u] + ad;
            v = (v > 0.f) ? v : NEG_SLOPE * v;
            float w = __expf(fminf(v, 60.f));
            sm += w;
#pragma unroll
            for (int r = 0; r < 8; r++) acc[r] += w * bf2f(gx[u][r]);
        }
    }
    for (; e < lim; e++) {
        int s = __shfl(myadj, gbase + e, 64);
        float v = a_src[s * HEADS + h] + ad;
        v = (v > 0.f) ? v : NEG_SLOPE * v;
        float w = __expf(fminf(v, 60.f));
        u16x8 g = *(const u16x8*)(hp + (size_t)s * (HEADS * OUT_D));
        sm += w;
#pragma unroll
        for (int r = 0; r < 8; r++) acc[r] += w * bf2f(g[r]);
    }
    for (int e2 = 32; e2 < cnt; e2++) {   // rare (deg >= 32, ~0.3% of nodes)
        int s = arow[e2];
        float v = a_src[s * HEADS + h] + ad;
        v = (v > 0.f) ? v : NEG_SLOPE * v;
        float w = __expf(fminf(v, 60.f));
        u16x8 g = *(const u16x8*)(hp + (size_t)s * (HEADS * OUT_D));
        sm += w;
#pragma unroll
        for (int r = 0; r < 8; r++) acc[r] += w * bf2f(g[r]);
    }

    // per-head normalize, then mean over heads (shfl_xor 8/16 stays inside the 32-lane group)
    const float inv = 1.f / (sm + 1e-16f);
#pragma unroll
    for (int r = 0; r < 8; r++) {
        acc[r] *= inv;
        acc[r] += __shfl_xor(acc[r], 8, 64);
        acc[r] += __shfl_xor(acc[r], 16, 64);
    }
    if (h == 0) {
        const f32x4 bg0 = *(const f32x4*)(bias_g + j * 8);
        const f32x4 bg1 = *(const f32x4*)(bias_g + j * 8 + 4);
        f32x4 o0 = { 0.25f * acc[0] + bg0[0], 0.25f * acc[1] + bg0[1],
                     0.25f * acc[2] + bg0[2], 0.25f * acc[3] + bg0[3] };
        f32x4 o1 = { 0.25f * acc[4] + bg1[0], 0.25f * acc[5] + bg1[1],
                     0.25f * acc[6] + bg1[2], 0.25f * acc[7] + bg1[3] };
        *(f32x4*)(out + (size_t)d * OUT_D + j * 8) = o0;
        *(f32x4*)(out + (size_t)d * OUT_D + j * 8 + 4) = o1;
    }
}

extern "C" void kernel_launch(void* const* d_in, const int* in_sizes, int n_in,
                              void* d_out, int out_size, void* d_ws, size_t ws_size,
                              hipStream_t stream) {
    const float* z       = (const float*)d_in[0];
    const float* W1      = (const float*)d_in[1];
    const float* b1      = (const float*)d_in[2];
    const float* W2      = (const float*)d_in[3];
    const float* b2      = (const float*)d_in[4];
    const float* Wg      = (const float*)d_in[5];
    const float* att_src = (const float*)d_in[6];
    const float* att_dst = (const float*)d_in[7];
    const float* bias_g  = (const float*)d_in[8];
    const int*   ei      = (const int*)d_in[9];
    float* out = (float*)d_out;

    char* ws = (char*)d_ws;
    size_t off = 0;
    auto carve = [&](size_t bytes) { void* p = ws + off; off += (bytes + 255) & ~(size_t)255; return p; };

    unsigned short* W1t = (unsigned short*)carve((size_t)H1 * LATENT * 2);
    unsigned short* W2t = (unsigned short*)carve((size_t)HIDDEN * H1 * 2);
    unsigned short* Wgt = (unsigned short*)carve((size_t)(HEADS * OUT_D) * HIDDEN * 2);
    unsigned short* hb  = (unsigned short*)carve((size_t)MPAD * HEADS * OUT_D * 2);
    float* a_src = (float*)carve((size_t)N_NODES * HEADS * 4);
    float* a_dst = (float*)carve((size_t)N_NODES * HEADS * 4);
    int*   cur   = (int*)carve((size_t)N_NODES * 4);
    unsigned short* adj = (unsigned short*)carve((size_t)MAX_IN * N_NODES * 2);

    // 3 dispatches (proven floor structure). R9: persistent scatter + u16 adj.
    prep_kernel<<<PREP_BLKS, 256, 0, stream>>>(W1, W2, Wg, W1t, W2t, Wgt, cur);

    mlp_scatter_kernel<<<MLP_BLOCKS + SCAT_BLOCKS, 256, 0, stream>>>(
        z, W1t, W2t, Wgt, b1, b2, att_src, att_dst, ei, cur, adj, hb, a_src, a_dst);

    fused_gat<<<N_NODES / 8, 256, 0, stream>>>(
        adj, cur, a_src, a_dst, hb, bias_g, out);
}

// Round 10
// 159.511 us; speedup vs baseline: 3.3107x; 1.0076x over previous
//
#include <hip/hip_runtime.h>
#include <hip/hip_bf16.h>

#define N_NODES 20000
#define MPAD    20096
#define E_EDGES 400000
#define LATENT 128
#define H1 256
#define HIDDEN 512
#define OUT_D 64
#define HEADS 4
#define NEG_SLOPE 0.2f
// fixed-pitch adjacency: deg ~ Binomial(400k, 1/20k) -> mean 20, sigma 4.47; 80 slots = 13+ sigma.
#define MAX_IN 80

// SESSION LESSONS (do not re-try):
//  R2: global f32 atomicAdd accumulation -> 100 us memory-side serialization. Recompute instead.
//  R6: hipLaunchCooperativeKernel is silently rejected under the harness's graph capture.
//  R7: manual grid barrier (agent-scope acquire spin + threadfence) -> per-XCD L2 invalidation
//      storm: FETCH 9->84 MB, 62->485 us. Dispatch boundaries are CHEAPER than in-kernel grid
//      sync on gfx950. 3-dispatch structure is the floor.
//  R9: persistent scatter (140 blocks = free co-residency slots) + u16 adj -> merged back to
//      pure-MLP floor (59.5 us).
//  R10 (this round): pin weight prefetches with sched_barrier(0) — attacks the prior session's
//      diagnosed "compiler sinks ALL register prefetches" policy. Last >=10 us theory-backed lever.

typedef __attribute__((ext_vector_type(8))) __bf16 bf16x8;
typedef __attribute__((ext_vector_type(4))) float f32x4;
typedef __attribute__((ext_vector_type(4))) unsigned short u16x4;
typedef __attribute__((ext_vector_type(8))) unsigned short u16x8;

__device__ __forceinline__ unsigned short f2bf(float f) {
    union { float f; unsigned int u; } v; v.f = f;
    unsigned int r = v.u + 0x7fffu + ((v.u >> 16) & 1u);  // RNE
    return (unsigned short)(r >> 16);
}
__device__ __forceinline__ float bf2f(unsigned short u) {
    union { unsigned int u; float f; } v; v.u = ((unsigned int)u) << 16;
    return v.f;
}

// ---------------- prep: LDS-tiled coalesced transpose-convert + cur zeroing -----------------------
#define W1_TILES 32
#define W2_TILES 128
#define WG_TILES 128
#define CUR_BLKS ((N_NODES + 255) / 256)   // 79
#define PREP_BLKS (W1_TILES + W2_TILES + WG_TILES + CUR_BLKS)
__global__ __launch_bounds__(256)
void prep_kernel(const float* __restrict__ W1, const float* __restrict__ W2,
                 const float* __restrict__ Wg,
                 unsigned short* __restrict__ W1t, unsigned short* __restrict__ W2t,
                 unsigned short* __restrict__ Wgt, int* __restrict__ cur) {
    int b = blockIdx.x;
    if (b >= W1_TILES + W2_TILES + WG_TILES) {
        int t = (b - (W1_TILES + W2_TILES + WG_TILES)) * 256 + threadIdx.x;
        if (t < N_NODES) cur[t] = 0;
        return;
    }
    const float* src; unsigned short* dst; int K, N, k0, n0;
    if (b < W1_TILES) {
        src = W1; dst = W1t; K = LATENT; N = H1;
        k0 = (b >> 3) * 32; n0 = (b & 7) * 32;
    } else if (b < W1_TILES + W2_TILES) {
        int t2 = b - W1_TILES;
        src = W2; dst = W2t; K = H1; N = HIDDEN;
        k0 = (t2 >> 4) * 32; n0 = (t2 & 15) * 32;
    } else {
        int t3 = b - W1_TILES - W2_TILES;
        src = Wg; dst = Wgt; K = HIDDEN; N = HEADS * OUT_D;
        k0 = (t3 >> 3) * 32; n0 = (t3 & 7) * 32;
    }
    __shared__ float tile[32][33];
    const int c = threadIdx.x & 31, r0 = threadIdx.x >> 5;
#pragma unroll
    for (int i = 0; i < 4; i++) {
        int r = r0 + i * 8;
        tile[r][c] = src[(size_t)(k0 + r) * N + n0 + c];       // coalesced read (c = n fast)
    }
    __syncthreads();
#pragma unroll
    for (int i = 0; i < 4; i++) {
        int r = r0 + i * 8;
        dst[(size_t)(n0 + r) * K + k0 + c] = f2bf(tile[c][r]); // coalesced write (c = k fast)
    }
}

// ---------------- merged: MLP (blocks 0..627) || persistent scatter (140 blocks) ------------------
// R3-proven shadow-overlap; R9 persistent scatter; R10: sched_barrier(0) pins weight prefetches.
#define TM 32
#define ZPITCH 136
#define XPITCH 264
#define X2PITCH 520
#define MLP_BLOCKS (MPAD / TM)                  // 628
#define SCAT_BLOCKS 140                         // 768 co-residency slots - 628 MLP blocks
__global__ __launch_bounds__(256, 4)
void mlp_scatter_kernel(const float* __restrict__ z,
                        const unsigned short* __restrict__ W1t,
                        const unsigned short* __restrict__ W2t,
                        const unsigned short* __restrict__ Wgt,
                        const float* __restrict__ b1, const float* __restrict__ b2,
                        const float* __restrict__ att_src, const float* __restrict__ att_dst,
                        const int* __restrict__ ei, int* __restrict__ cur,
                        unsigned short* __restrict__ adj,
                        unsigned short* __restrict__ hb,
                        float* __restrict__ a_src, float* __restrict__ a_dst) {
    __shared__ unsigned short x2s[TM * X2PITCH];   // 33.3 KB; first 8.7 KB aliased as zbf
    __shared__ unsigned short x1s[TM * XPITCH];    // 16.9 KB (50.2 KB total)

    if (blockIdx.x >= MLP_BLOCKS) {
        // persistent scatter: 140 blocks grid-stride all 400k edges (~11 edges/thread, coalesced)
        int t0 = (blockIdx.x - MLP_BLOCKS) * 256 + threadIdx.x;
        for (int t = t0; t < E_EDGES; t += SCAT_BLOCKS * 256) {
            int s = ei[t], d = ei[E_EDGES + t];
            int idx = atomicAdd(&cur[d], 1);
            idx = min(idx, MAX_IN - 1);            // statistically unreachable clamp
            adj[d * MAX_IN + idx] = (unsigned short)s;   // node ids < 20000 < 65536
        }
        return;
    }

    unsigned short* zbf = x2s;
    const int tid = threadIdx.x;
    const int wave = tid >> 6, lane = tid & 63;
    const int m0 = blockIdx.x * TM;
    const int fr = lane & 15, q = lane >> 4;

#define LDW1(kt, t)      (*(const bf16x8*)(W1t + (size_t)(nb1 + (t) * 16 + fr) * LATENT + (kt) * 32 + q * 8))
#define LDW2H(nh, kt, t) (*(const bf16x8*)(W2t + (size_t)(nb2 + (nh) * 64 + (t) * 16 + fr) * H1 + (kt) * 32 + q * 8))
#define LDW3(kt, t)      (*(const bf16x8*)(Wgt + (size_t)(nb3 + (t) * 16 + fr) * HIDDEN + (kt) * 32 + q * 8))

    const int nb1 = wave * 64;
    const int nb2 = wave * 128;
    const int head = wave;
    const int nb3 = wave * 64;

    bf16x8 w1a[4], w1b[4];
#pragma unroll
    for (int t = 0; t < 4; t++) w1a[t] = LDW1(0, t);

    {
        const int r = tid >> 3, c0 = (tid & 7) * 16;
        const int zrow = min(m0 + r, N_NODES - 1);
        const float* zp = z + (size_t)zrow * LATENT + c0;
#pragma unroll
        for (int i = 0; i < 4; i++) {
            f32x4 v = *(const f32x4*)(zp + i * 4);
            u16x4 p = { f2bf(v[0]), f2bf(v[1]), f2bf(v[2]), f2bf(v[3]) };
            *(u16x4*)(zbf + r * ZPITCH + c0 + i * 4) = p;
        }
    }
    __syncthreads();

    // ---- layer 1: K=128 (4 kt) ----
    f32x4 acc1[2][4] = {};
#pragma unroll
    for (int kt = 0; kt < 4; kt++) {
        bf16x8* wc = (kt & 1) ? w1b : w1a;
        bf16x8* wn = (kt & 1) ? w1a : w1b;
        if (kt < 3) {
#pragma unroll
            for (int t = 0; t < 4; t++) wn[t] = LDW1(kt + 1, t);
        }
        // R10: forbid the scheduler from sinking the prefetch loads below this point
        // (prior session: "compiler sinks ALL register prefetches" = the diagnosed latency chain).
        __builtin_amdgcn_sched_barrier(0);
        bf16x8 af[2];
#pragma unroll
        for (int t = 0; t < 2; t++)
            af[t] = *(const bf16x8*)(zbf + (t * 16 + fr) * ZPITCH + kt * 32 + q * 8);
#pragma unroll
        for (int mt = 0; mt < 2; mt++)
#pragma unroll
            for (int nt = 0; nt < 4; nt++)
                acc1[mt][nt] = __builtin_amdgcn_mfma_f32_16x16x32_bf16(
                    wc[nt], af[mt], acc1[mt][nt], 0, 0, 0);
    }

    bf16x8 w2a[4], w2b[4];
#pragma unroll
    for (int t = 0; t < 4; t++) w2a[t] = LDW2H(0, 0, t);

    // layer-1 epilogue -> x1s
#pragma unroll
    for (int nt = 0; nt < 4; nt++) {
        const int n = nb1 + nt * 16 + q * 4;
        const f32x4 bv = *(const f32x4*)(b1 + n);
#pragma unroll
        for (int mt = 0; mt < 2; mt++) {
            u16x4 p;
#pragma unroll
            for (int r = 0; r < 4; r++) p[r] = f2bf(fmaxf(acc1[mt][nt][r] + bv[r], 0.f));
            *(u16x4*)(x1s + (mt * 16 + fr) * XPITCH + n) = p;
        }
    }
    __syncthreads();

    // ---- layer 2: K=256 (8 kt), two sequential 64-col halves ----
#pragma unroll
    for (int nh = 0; nh < 2; nh++) {
        if (nh == 1) {
#pragma unroll
            for (int t = 0; t < 4; t++) w2a[t] = LDW2H(1, 0, t);
        }
        f32x4 acc2[2][4] = {};
#pragma unroll
        for (int kt = 0; kt < 8; kt++) {
            bf16x8* wc = (kt & 1) ? w2b : w2a;
            bf16x8* wn = (kt & 1) ? w2a : w2b;
            if (kt < 7) {
#pragma unroll
                for (int t = 0; t < 4; t++) wn[t] = LDW2H(nh, kt + 1, t);
            }
            __builtin_amdgcn_sched_barrier(0);   // R10: pin prefetch issue point
            bf16x8 af[2];
#pragma unroll
            for (int t = 0; t < 2; t++)
                af[t] = *(const bf16x8*)(x1s + (t * 16 + fr) * XPITCH + kt * 32 + q * 8);
#pragma unroll
            for (int mt = 0; mt < 2; mt++)
#pragma unroll
                for (int nt = 0; nt < 4; nt++)
                    acc2[mt][nt] = __builtin_amdgcn_mfma_f32_16x16x32_bf16(
                        wc[nt], af[mt], acc2[mt][nt], 0, 0, 0);
        }
#pragma unroll
        for (int nt = 0; nt < 4; nt++) {
            const int n = nb2 + nh * 64 + nt * 16 + q * 4;
            const f32x4 bv = *(const f32x4*)(b2 + n);
#pragma unroll
            for (int mt = 0; mt < 2; mt++) {
                u16x4 p;
#pragma unroll
                for (int r = 0; r < 4; r++) p[r] = f2bf(fmaxf(acc2[mt][nt][r] + bv[r], 0.f));
                *(u16x4*)(x2s + (mt * 16 + fr) * X2PITCH + n) = p;
            }
        }
    }

    bf16x8 w3a[4], w3b[4];
#pragma unroll
    for (int t = 0; t < 4; t++) w3a[t] = LDW3(0, t);
    __syncthreads();

    // ---- layer 3: K=512 (16 kt) + att epilogue ----
    f32x4 acc3[2][4] = {};
#pragma unroll
    for (int kt = 0; kt < 16; kt++) {
        bf16x8* wc = (kt & 1) ? w3b : w3a;
        bf16x8* wn = (kt & 1) ? w3a : w3b;
        if (kt < 15) {
#pragma unroll
            for (int t = 0; t < 4; t++) wn[t] = LDW3(kt + 1, t);
        }
        __builtin_amdgcn_sched_barrier(0);       // R10: pin prefetch issue point
        bf16x8 af[2];
#pragma unroll
        for (int t = 0; t < 2; t++)
            af[t] = *(const bf16x8*)(x2s + (t * 16 + fr) * X2PITCH + kt * 32 + q * 8);
#pragma unroll
        for (int mt = 0; mt < 2; mt++)
#pragma unroll
            for (int nt = 0; nt < 4; nt++)
                acc3[mt][nt] = __builtin_amdgcn_mfma_f32_16x16x32_bf16(
                    wc[nt], af[mt], acc3[mt][nt], 0, 0, 0);
    }

    {
        f32x4 asv[4], adv[4];
#pragma unroll
        for (int nt = 0; nt < 4; nt++) {
            asv[nt] = *(const f32x4*)(att_src + head * OUT_D + nt * 16 + q * 4);
            adv[nt] = *(const f32x4*)(att_dst + head * OUT_D + nt * 16 + q * 4);
        }
#pragma unroll
        for (int mt = 0; mt < 2; mt++) {
            const int row = m0 + mt * 16 + fr;
            float vs = 0.f, vd = 0.f;
#pragma unroll
            for (int nt = 0; nt < 4; nt++) {
                u16x4 p;
#pragma unroll
                for (int r = 0; r < 4; r++) {
                    float x = acc3[mt][nt][r];
                    p[r] = f2bf(x);
                    vs += x * asv[nt][r];
                    vd += x * adv[nt][r];
                }
                *(u16x4*)(hb + (size_t)row * (HEADS * OUT_D) + head * OUT_D + nt * 16 + q * 4) = p;
            }
            vs += __shfl_xor(vs, 16, 64); vs += __shfl_xor(vs, 32, 64);
            vd += __shfl_xor(vd, 16, 64); vd += __shfl_xor(vd, 32, 64);
            if (q == 0 && row < N_NODES) {
                a_src[row * HEADS + head] = vs;
                a_dst[row * HEADS + head] = vd;
            }
        }
    }
#undef LDW1
#undef LDW2H
#undef LDW3
}

// ---------------- single-pass gather-aggregate, adj broadcast via shfl (R5-proven, u16 adj) -------
__global__ __launch_bounds__(256)
void fused_gat(const unsigned short* __restrict__ adj, const int* __restrict__ cur,
               const float* __restrict__ a_src, const float* __restrict__ a_dst,
               const unsigned short* __restrict__ hb,
               const float* __restrict__ bias_g, float* __restrict__ out) {
    const int wave = threadIdx.x >> 6, lane = threadIdx.x & 63;
    const int grp = lane >> 5, sl = lane & 31;
    const int d = blockIdx.x * 8 + wave * 2 + grp;   // 2500 blocks x 8 nodes
    const int h = sl >> 3, j = sl & 7;
    const int cnt = min(cur[d], MAX_IN);
    const unsigned short* arow = adj + d * MAX_IN;
    const int gbase = grp * 32;                      // shfl source-lane base for this group

    // one coalesced adjacency load: lane sl holds edge sl (64 B per 32-lane group)
    int myadj = (sl < cnt) ? (int)arow[sl] : 0;

    const float ad = a_dst[d * HEADS + h];
    const unsigned short* hp = hb + h * OUT_D + j * 8;

    // self-loop seeds accumulators
    float vself = a_src[d * HEADS + h] + ad;
    vself = (vself > 0.f) ? vself : NEG_SLOPE * vself;
    float sm = __expf(fminf(vself, 60.f));
    u16x8 gs = *(const u16x8*)(hp + (size_t)d * (HEADS * OUT_D));
    float acc[8];
#pragma unroll
    for (int r = 0; r < 8; r++) acc[r] = sm * bf2f(gs[r]);

    const int lim = cnt < 32 ? cnt : 32;
    int e = 0;
    for (; e + 7 < lim; e += 8) {
        int sx[8]; float fx[8]; u16x8 gx[8];
#pragma unroll
        for (int u = 0; u < 8; u++) sx[u] = __shfl(myadj, gbase + e + u, 64);
#pragma unroll
        for (int u = 0; u < 8; u++) fx[u] = a_src[sx[u] * HEADS + h];
#pragma unroll
        for (int u = 0; u < 8; u++) gx[u] = *(const u16x8*)(hp + (size_t)sx[u] * (HEADS * OUT_D));
#pragma unroll
        for (int u = 0; u < 8; u++) {
            float v = fx[u] + ad;
            v = (v > 0.f) ? v : NEG_SLOPE * v;
            float w = __expf(fminf(v, 60.f));
            sm += w;
#pragma unroll
            for (int r = 0; r < 8; r++) acc[r] += w * bf2f(gx[u][r]);
        }
    }
    for (; e + 3 < lim; e += 4) {
        int sx[4]; float fx[4]; u16x8 gx[4];
#pragma unroll
        for (int u = 0; u < 4; u++) sx[u] = __shfl(myadj, gbase + e + u, 64);
#pragma unroll
        for (int u = 0; u < 4; u++) fx[u] = a_src[sx[u] * HEADS + h];
#pragma unroll
        for (int u = 0; u < 4; u++) gx[u] = *(const u16x8*)(hp + (size_t)sx[u] * (HEADS * OUT_D));
#pragma unroll
        for (int u = 0; u < 4; u++) {
            float v = fx[u] + ad;
            v = (v > 0.f) ? v : NEG_SLOPE * v;
            float w = __expf(fminf(v, 60.f));
            sm += w;
#pragma unroll
            for (int r = 0; r < 8; r++) acc[r] += w * bf2f(gx[u][r]);
        }
    }
    for (; e < lim; e++) {
        int s = __shfl(myadj, gbase + e, 64);
        float v = a_src[s * HEADS + h] + ad;
        v = (v > 0.f) ? v : NEG_SLOPE * v;
        float w = __expf(fminf(v, 60.f));
        u16x8 g = *(const u16x8*)(hp + (size_t)s * (HEADS * OUT_D));
        sm += w;
#pragma unroll
        for (int r = 0; r < 8; r++) acc[r] += w * bf2f(g[r]);
    }
    for (int e2 = 32; e2 < cnt; e2++) {   // rare (deg >= 32, ~0.3% of nodes)
        int s = arow[e2];
        float v = a_src[s * HEADS + h] + ad;
        v = (v > 0.f) ? v : NEG_SLOPE * v;
        float w = __expf(fminf(v, 60.f));
        u16x8 g = *(const u16x8*)(hp + (size_t)s * (HEADS * OUT_D));
        sm += w;
#pragma unroll
        for (int r = 0; r < 8; r++) acc[r] += w * bf2f(g[r]);
    }

    // per-head normalize, then mean over heads (shfl_xor 8/16 stays inside the 32-lane group)
    const float inv = 1.f / (sm + 1e-16f);
#pragma unroll
    for (int r = 0; r < 8; r++) {
        acc[r] *= inv;
        acc[r] += __shfl_xor(acc[r], 8, 64);
        acc[r] += __shfl_xor(acc[r], 16, 64);
    }
    if (h == 0) {
        const f32x4 bg0 = *(const f32x4*)(bias_g + j * 8);
        const f32x4 bg1 = *(const f32x4*)(bias_g + j * 8 + 4);
        f32x4 o0 = { 0.25f * acc[0] + bg0[0], 0.25f * acc[1] + bg0[1],
                     0.25f * acc[2] + bg0[2], 0.25f * acc[3] + bg0[3] };
        f32x4 o1 = { 0.25f * acc[4] + bg1[0], 0.25f * acc[5] + bg1[1],
                     0.25f * acc[6] + bg1[2], 0.25f * acc[7] + bg1[3] };
        *(f32x4*)(out + (size_t)d * OUT_D + j * 8) = o0;
        *(f32x4*)(out + (size_t)d * OUT_D + j * 8 + 4) = o1;
    }
}

extern "C" void kernel_launch(void* const* d_in, const int* in_sizes, int n_in,
                              void* d_out, int out_size, void* d_ws, size_t ws_size,
                              hipStream_t stream) {
    const float* z       = (const float*)d_in[0];
    const float* W1      = (const float*)d_in[1];
    const float* b1      = (const float*)d_in[2];
    const float* W2      = (const float*)d_in[3];
    const float* b2      = (const float*)d_in[4];
    const float* Wg      = (const float*)d_in[5];
    const float* att_src = (const float*)d_in[6];
    const float* att_dst = (const float*)d_in[7];
    const float* bias_g  = (const float*)d_in[8];
    const int*   ei      = (const int*)d_in[9];
    float* out = (float*)d_out;

    char* ws = (char*)d_ws;
    size_t off = 0;
    auto carve = [&](size_t bytes) { void* p = ws + off; off += (bytes + 255) & ~(size_t)255; return p; };

    unsigned short* W1t = (unsigned short*)carve((size_t)H1 * LATENT * 2);
    unsigned short* W2t = (unsigned short*)carve((size_t)HIDDEN * H1 * 2);
    unsigned short* Wgt = (unsigned short*)carve((size_t)(HEADS * OUT_D) * HIDDEN * 2);
    unsigned short* hb  = (unsigned short*)carve((size_t)MPAD * HEADS * OUT_D * 2);
    float* a_src = (float*)carve((size_t)N_NODES * HEADS * 4);
    float* a_dst = (float*)carve((size_t)N_NODES * HEADS * 4);
    int*   cur   = (int*)carve((size_t)N_NODES * 4);
    unsigned short* adj = (unsigned short*)carve((size_t)MAX_IN * N_NODES * 2);

    // 3 dispatches (proven floor structure). R10: sched_barrier-pinned weight prefetches.
    prep_kernel<<<PREP_BLKS, 256, 0, stream>>>(W1, W2, Wg, W1t, W2t, Wgt, cur);

    mlp_scatter_kernel<<<MLP_BLOCKS + SCAT_BLOCKS, 256, 0, stream>>>(
        z, W1t, W2t, Wgt, b1, b2, att_src, att_dst, ei, cur, adj, hb, a_src, a_dst);

    fused_gat<<<N_NODES / 8, 256, 0, stream>>>(
        adj, cur, a_src, a_dst, hb, bias_g, out);
}